// Round 1
// baseline (550.198 us; speedup 1.0000x reference)
//
#include <hip/hip_runtime.h>

// ---------------- MLP layer: out[b, j] = act( A[b,:] @ W[:, j] + bias[j] ) ----------------
// A: [B, K] row-major, W: [K, N] row-major, out: [B, N]
// grid.x = ceil(N/256), grid.y = B/BG, block = 256
template<int BG, bool RELU>
__global__ __launch_bounds__(256) void mlp_layer(
    const float* __restrict__ A, const float* __restrict__ W,
    const float* __restrict__ bias, float* __restrict__ out, int K, int N) {
  __shared__ float sA[BG][1024];
  const int tid = threadIdx.x;
  const int j   = blockIdx.x * 256 + tid;
  const int b0  = blockIdx.y * BG;

  for (int g = 0; g < BG; ++g)
    for (int k = tid; k < K; k += 256)
      sA[g][k] = A[(size_t)(b0 + g) * K + k];
  __syncthreads();

  float acc[BG];
#pragma unroll
  for (int g = 0; g < BG; ++g) acc[g] = 0.f;

  if (j < N) {
    const float* wp = W + j;
#pragma unroll 4
    for (int k = 0; k < K; ++k) {
      float w = wp[(size_t)k * N];
#pragma unroll
      for (int g = 0; g < BG; ++g) acc[g] = fmaf(sA[g][k], w, acc[g]);
    }
    const float bj = bias[j];
#pragma unroll
    for (int g = 0; g < BG; ++g) {
      float v = acc[g] + bj;
      out[(size_t)(b0 + g) * N + j] = RELU ? fmaxf(v, 0.f) : v;
    }
  }
}

// ---------------- ccc[b,c] = Re( conj(theta_b)^T T[b,c] theta_b )  (raw, no /THRESHOLD_W) ----
// grid = B*C = 8192 blocks, block = 256
__global__ __launch_bounds__(256) void ccc_kernel(
    const float* __restrict__ Tr, const float* __restrict__ Ti,
    const float* __restrict__ theta1, float* __restrict__ ccc) {
  const int bc = blockIdx.x;
  const int b  = bc >> 6;
  const int tid = threadIdx.x;

  __shared__ __align__(16) float sx[104];
  __shared__ __align__(16) float sy[104];
  if (tid < 100) {
    float tr = theta1[b * 264 + tid];
    float ti = theta1[b * 264 + 100 + tid];
    float inv = rsqrtf(fmaf(tr, tr, ti * ti));
    sx[tid] = tr * inv;
    sy[tid] = ti * inv;
  }
  __syncthreads();

  const float4* Tr4 = reinterpret_cast<const float4*>(Tr + (size_t)bc * 10000);
  const float4* Ti4 = reinterpret_cast<const float4*>(Ti + (size_t)bc * 10000);

  float acc = 0.f;
  // 2500 float4 elements; element index 4*i -> n = i/25, m0 = (i%25)*4 (rows are 100 = 25 float4s)
  for (int i = tid; i < 2500; i += 256) {
    float4 t = Tr4[i];
    float4 u = Ti4[i];
    int n  = i / 25;
    int m0 = (i - n * 25) * 4;
    float xn = sx[n], yn = sy[n];
    float4 xm = *reinterpret_cast<const float4*>(&sx[m0]);
    float4 ym = *reinterpret_cast<const float4*>(&sy[m0]);
    // Re = Tr*(xn*xm + yn*ym) + Ti*(yn*xm - xn*ym)
    acc = fmaf(t.x, fmaf(xn, xm.x, yn * ym.x), acc);
    acc = fmaf(u.x, fmaf(yn, xm.x, -(xn * ym.x)), acc);
    acc = fmaf(t.y, fmaf(xn, xm.y, yn * ym.y), acc);
    acc = fmaf(u.y, fmaf(yn, xm.y, -(xn * ym.y)), acc);
    acc = fmaf(t.z, fmaf(xn, xm.z, yn * ym.z), acc);
    acc = fmaf(u.z, fmaf(yn, xm.z, -(xn * ym.z)), acc);
    acc = fmaf(t.w, fmaf(xn, xm.w, yn * ym.w), acc);
    acc = fmaf(u.w, fmaf(yn, xm.w, -(xn * ym.w)), acc);
  }

  // block reduce (4 waves)
  for (int off = 32; off; off >>= 1) acc += __shfl_down(acc, off);
  __shared__ float sred[4];
  if ((tid & 63) == 0) sred[tid >> 6] = acc;
  __syncthreads();
  if (tid == 0) ccc[bc] = (sred[0] + sred[1]) + (sred[2] + sred[3]);
}

// ---------------- finalize: scale = sqrt(THRESHOLD_W / max_c ccc_raw); write output --------
// grid = 128 blocks (one per b), block = 256
__global__ __launch_bounds__(256) void finalize_kernel(
    const float* __restrict__ theta1, const float* __restrict__ ccc,
    float* __restrict__ out) {
  const int b = blockIdx.x;
  const int tid = threadIdx.x;
  __shared__ float s_scale;
  if (tid < 64) {
    float v = ccc[b * 64 + tid];
    for (int off = 32; off; off >>= 1) v = fmaxf(v, __shfl_down(v, off));
    if (tid == 0) s_scale = sqrtf(1e-15f / v);
  }
  __syncthreads();
  const float scale = s_scale;
  for (int j = tid; j < 264; j += 256) {
    float o;
    if (j < 200) {
      int n = (j < 100) ? j : (j - 100);
      float tr = theta1[b * 264 + n];
      float ti = theta1[b * 264 + 100 + n];
      float inv = rsqrtf(fmaf(tr, tr, ti * ti));
      o = ((j < 100) ? tr : ti) * inv * scale;
    } else {
      o = theta1[b * 264 + j];
    }
    out[b * 264 + j] = o;
  }
}

extern "C" void kernel_launch(void* const* d_in, const int* in_sizes, int n_in,
                              void* d_out, int out_size, void* d_ws, size_t ws_size,
                              hipStream_t stream) {
  const float* sample1 = (const float*)d_in[0];
  // d_in[1] = sample2 (unused by reference)
  const float* Tr = (const float*)d_in[2];
  const float* Ti = (const float*)d_in[3];
  const float* W1 = (const float*)d_in[4];  const float* b1 = (const float*)d_in[5];
  const float* W2 = (const float*)d_in[6];  const float* b2 = (const float*)d_in[7];
  const float* W3 = (const float*)d_in[8];  const float* b3 = (const float*)d_in[9];
  const float* W4 = (const float*)d_in[10]; const float* b4 = (const float*)d_in[11];
  const float* W5 = (const float*)d_in[12]; const float* b5 = (const float*)d_in[13];

  float* ws = (float*)d_ws;
  float* hA = ws;                       // 128*1024
  float* hB = ws + 128 * 1024;          // 128*1024
  float* th = ws + 2 * 128 * 1024;      // 128*264 (theta1)
  float* cc = th + 128 * 264;           // 8192

  float* out = (float*)d_out;

  mlp_layer<2, true ><<<dim3(4, 64), 256, 0, stream>>>(sample1, W1, b1, hA, 303, 1024);
  mlp_layer<2, true ><<<dim3(4, 64), 256, 0, stream>>>(hA, W2, b2, hB, 1024, 1024);
  mlp_layer<2, true ><<<dim3(4, 64), 256, 0, stream>>>(hB, W3, b3, hA, 1024, 1024);
  mlp_layer<2, true ><<<dim3(2, 64), 256, 0, stream>>>(hA, W4, b4, hB, 1024, 512);
  mlp_layer<2, false><<<dim3(2, 64), 256, 0, stream>>>(hB, W5, b5, th, 512, 264);

  ccc_kernel<<<dim3(128 * 64), 256, 0, stream>>>(Tr, Ti, th, cc);
  finalize_kernel<<<dim3(128), 256, 0, stream>>>(th, cc, out);
}

// Round 2
// 193.900 us; speedup vs baseline: 2.8375x; 2.8375x over previous
//
#include <hip/hip_runtime.h>

#define B_ 128   // batch

// ---------------- split-K MLP partial ----------------
// P[z][b][j] = sum_{k in slice z} act(in)[b,k] * W[k,j]
// act(in)[b,k] = (NSUM==0) ? A[b,k] : relu(bias_in[k] + sum_{s<NSUM} A[s][b][k])
// grid = (ceil(N/256), B/BG, SPLITK), block = 256
template<int BG, int NSUM, int KS_MAX>
__global__ __launch_bounds__(256) void mlp_split(
    const float* __restrict__ A, const float* __restrict__ bias_in,
    const float* __restrict__ W, float* __restrict__ P,
    int K, int N, int kslice) {
  __shared__ float sA[BG][KS_MAX];
  const int tid = threadIdx.x;
  const int j   = blockIdx.x * 256 + tid;
  const int b0  = blockIdx.y * BG;
  const int k0  = blockIdx.z * kslice;
  const int k1  = min(K, k0 + kslice);
  const int klen = k1 - k0;

  for (int g = 0; g < BG; ++g) {
    for (int k = tid; k < klen; k += 256) {
      float v;
      if (NSUM == 0) {
        v = A[(size_t)(b0 + g) * K + k0 + k];
      } else {
        v = bias_in[k0 + k];
#pragma unroll
        for (int s = 0; s < NSUM; ++s)
          v += A[(size_t)s * B_ * K + (size_t)(b0 + g) * K + k0 + k];
        v = fmaxf(v, 0.f);
      }
      sA[g][k] = v;
    }
  }
  __syncthreads();

  if (j >= N) return;
  float acc[BG];
#pragma unroll
  for (int g = 0; g < BG; ++g) acc[g] = 0.f;

  const float* wp = W + (size_t)k0 * N + j;
#pragma unroll 8
  for (int k = 0; k < klen; ++k) {
    float w = wp[(size_t)k * N];
#pragma unroll
    for (int g = 0; g < BG; ++g) acc[g] = fmaf(sA[g][k], w, acc[g]);
  }
  float* pp = P + (size_t)blockIdx.z * B_ * N;
#pragma unroll
  for (int g = 0; g < BG; ++g) pp[(size_t)(b0 + g) * N + j] = acc[g];
}

// ---------------- ccc[b,c] = Re( conj(theta)^T T theta )  (raw) ----------------
// theta1 reconstructed from 4 partials P5 + b5; grid = B*C, block = 256
__global__ __launch_bounds__(256) void ccc_kernel(
    const float* __restrict__ Tr, const float* __restrict__ Ti,
    const float* __restrict__ P5, const float* __restrict__ b5,
    float* __restrict__ ccc) {
  const int bc = blockIdx.x;
  const int b  = bc >> 6;
  const int tid = threadIdx.x;

  __shared__ __align__(16) float sx[104];
  __shared__ __align__(16) float sy[104];
  if (tid < 100) {
    float tr = b5[tid], ti = b5[100 + tid];
#pragma unroll
    for (int s = 0; s < 4; ++s) {
      tr += P5[(size_t)s * B_ * 264 + b * 264 + tid];
      ti += P5[(size_t)s * B_ * 264 + b * 264 + 100 + tid];
    }
    float inv = rsqrtf(fmaf(tr, tr, ti * ti));
    sx[tid] = tr * inv;
    sy[tid] = ti * inv;
  }
  __syncthreads();

  const float4* Tr4 = reinterpret_cast<const float4*>(Tr + (size_t)bc * 10000);
  const float4* Ti4 = reinterpret_cast<const float4*>(Ti + (size_t)bc * 10000);

  float acc = 0.f;
  for (int i = tid; i < 2500; i += 256) {
    float4 t = Tr4[i];
    float4 u = Ti4[i];
    int n  = i / 25;
    int m0 = (i - n * 25) * 4;
    float xn = sx[n], yn = sy[n];
    float4 xm = *reinterpret_cast<const float4*>(&sx[m0]);
    float4 ym = *reinterpret_cast<const float4*>(&sy[m0]);
    acc = fmaf(t.x, fmaf(xn, xm.x, yn * ym.x), acc);
    acc = fmaf(u.x, fmaf(yn, xm.x, -(xn * ym.x)), acc);
    acc = fmaf(t.y, fmaf(xn, xm.y, yn * ym.y), acc);
    acc = fmaf(u.y, fmaf(yn, xm.y, -(xn * ym.y)), acc);
    acc = fmaf(t.z, fmaf(xn, xm.z, yn * ym.z), acc);
    acc = fmaf(u.z, fmaf(yn, xm.z, -(xn * ym.z)), acc);
    acc = fmaf(t.w, fmaf(xn, xm.w, yn * ym.w), acc);
    acc = fmaf(u.w, fmaf(yn, xm.w, -(xn * ym.w)), acc);
  }

  for (int off = 32; off; off >>= 1) acc += __shfl_down(acc, off);
  __shared__ float sred[4];
  if ((tid & 63) == 0) sred[tid >> 6] = acc;
  __syncthreads();
  if (tid == 0) ccc[bc] = (sred[0] + sred[1]) + (sred[2] + sred[3]);
}

// ---------------- finalize ----------------
// grid = B blocks, block = 256
__global__ __launch_bounds__(256) void finalize_kernel(
    const float* __restrict__ P5, const float* __restrict__ b5,
    const float* __restrict__ ccc, float* __restrict__ out) {
  const int b = blockIdx.x;
  const int tid = threadIdx.x;
  __shared__ float s_t1[264];
  __shared__ float s_scale;

  for (int j = tid; j < 264; j += 256) {
    float v = b5[j];
#pragma unroll
    for (int s = 0; s < 4; ++s)
      v += P5[(size_t)s * B_ * 264 + b * 264 + j];
    s_t1[j] = v;
  }
  if (tid < 64) {
    float v = ccc[b * 64 + tid];
    for (int off = 32; off; off >>= 1) v = fmaxf(v, __shfl_down(v, off));
    if (tid == 0) s_scale = sqrtf(1e-15f / v);
  }
  __syncthreads();

  const float scale = s_scale;
  for (int j = tid; j < 264; j += 256) {
    float o;
    if (j < 200) {
      int n = (j < 100) ? j : (j - 100);
      float tr = s_t1[n];
      float ti = s_t1[100 + n];
      float inv = rsqrtf(fmaf(tr, tr, ti * ti));
      o = ((j < 100) ? tr : ti) * inv * scale;
    } else {
      o = s_t1[j];
    }
    out[b * 264 + j] = o;
  }
}

extern "C" void kernel_launch(void* const* d_in, const int* in_sizes, int n_in,
                              void* d_out, int out_size, void* d_ws, size_t ws_size,
                              hipStream_t stream) {
  const float* sample1 = (const float*)d_in[0];
  const float* Tr = (const float*)d_in[2];
  const float* Ti = (const float*)d_in[3];
  const float* W1 = (const float*)d_in[4];  const float* b1 = (const float*)d_in[5];
  const float* W2 = (const float*)d_in[6];  const float* b2 = (const float*)d_in[7];
  const float* W3 = (const float*)d_in[8];  const float* b3 = (const float*)d_in[9];
  const float* W4 = (const float*)d_in[10]; const float* b4 = (const float*)d_in[11];
  const float* W5 = (const float*)d_in[12]; const float* b5 = (const float*)d_in[13];

  float* ws = (float*)d_ws;
  float* Pa = ws;                        // 8*128*1024 = 1,048,576 floats
  float* Pb = Pa + 8 * B_ * 1024;        // 8*128*1024
  float* P5 = Pb + 8 * B_ * 1024;        // 4*128*264
  float* cc = P5 + 4 * B_ * 264;         // 8192

  float* out = (float*)d_out;

  // L1: [128,303]@[303,1024], raw input, SPLITK=8, kslice=38
  mlp_split<2, 0, 40 ><<<dim3(4, 64, 8), 256, 0, stream>>>(sample1, nullptr, W1, Pa, 303, 1024, 38);
  // L2: relu(Pa+b1) @ W2 -> Pb
  mlp_split<2, 8, 128><<<dim3(4, 64, 8), 256, 0, stream>>>(Pa, b1, W2, Pb, 1024, 1024, 128);
  // L3: relu(Pb+b2) @ W3 -> Pa
  mlp_split<2, 8, 128><<<dim3(4, 64, 8), 256, 0, stream>>>(Pb, b2, W3, Pa, 1024, 1024, 128);
  // L4: relu(Pa+b3) @ W4 -> Pb  (N=512)
  mlp_split<2, 8, 128><<<dim3(2, 64, 8), 256, 0, stream>>>(Pa, b3, W4, Pb, 1024, 512, 128);
  // L5: relu(Pb+b4) @ W5 -> P5  (N=264, SPLITK=4)
  mlp_split<2, 8, 128><<<dim3(2, 64, 4), 256, 0, stream>>>(Pb, b4, W5, P5, 512, 264, 128);

  ccc_kernel<<<dim3(B_ * 64), 256, 0, stream>>>(Tr, Ti, P5, b5, cc);
  finalize_kernel<<<dim3(B_), 256, 0, stream>>>(P5, b5, cc, out);
}

// Round 3
// 188.357 us; speedup vs baseline: 2.9210x; 1.0294x over previous
//
#include <hip/hip_runtime.h>

#define B_ 128   // batch

// ---------------- split-K MLP layer, float4 cols ----------------
// P[z][b][j] = sum_{k in slice z} act[b,k] * W[k,j]
// act[b,k] = (NSUM==0) ? A[b,k] : relu(bias_in[k] + sum_s A[s][b][k])
// grid = (1, B_/BG, SPLITK), block = THREADS
// THREADS/(N_T/4) row-groups; each thread computes RPT rows x 4 cols.
template<int THREADS, int BG, int NSUM, int N_T, int KS>
__global__ __launch_bounds__(THREADS) void mlp4(
    const float* __restrict__ A, const float* __restrict__ bias_in,
    const float* __restrict__ W, float* __restrict__ P, int K) {
  constexpr int G   = N_T / 4;        // col groups
  constexpr int NRG = THREADS / G;    // row groups
  constexpr int RPT = BG / NRG;       // rows per thread
  __shared__ float sA[BG][KS];

  const int tid = threadIdx.x;
  const int cg  = tid % G;
  const int rg  = tid / G;
  const int b0  = blockIdx.y * BG;
  const int k0  = blockIdx.z * KS;
  const int klen = (NSUM == 0) ? min(K - k0, KS) : KS;

  if (NSUM == 0) {
    for (int g = 0; g < BG; ++g)
      for (int k = tid; k < klen; k += THREADS)
        sA[g][k] = A[(size_t)(b0 + g) * K + k0 + k];
  } else {
    constexpr int K4 = KS / 4;
    for (int idx = tid; idx < BG * K4; idx += THREADS) {
      int g = idx / K4, k4 = idx % K4;
      float4 v = *(const float4*)(bias_in + k0 + 4 * k4);
      for (int s = 0; s < NSUM; ++s) {
        float4 p = *(const float4*)(A + ((size_t)s * B_ + b0 + g) * K + k0 + 4 * k4);
        v.x += p.x; v.y += p.y; v.z += p.z; v.w += p.w;
      }
      v.x = fmaxf(v.x, 0.f); v.y = fmaxf(v.y, 0.f);
      v.z = fmaxf(v.z, 0.f); v.w = fmaxf(v.w, 0.f);
      *(float4*)&sA[g][4 * k4] = v;
    }
  }
  __syncthreads();

  float4 acc[RPT];
#pragma unroll
  for (int r = 0; r < RPT; ++r) acc[r] = make_float4(0.f, 0.f, 0.f, 0.f);

  const float* wp = W + (size_t)k0 * N_T + 4 * cg;
#pragma unroll 4
  for (int k = 0; k < klen; ++k) {
    float4 w = *(const float4*)wp;
    wp += N_T;
#pragma unroll
    for (int r = 0; r < RPT; ++r) {
      float a = sA[rg * RPT + r][k];
      acc[r].x = fmaf(a, w.x, acc[r].x);
      acc[r].y = fmaf(a, w.y, acc[r].y);
      acc[r].z = fmaf(a, w.z, acc[r].z);
      acc[r].w = fmaf(a, w.w, acc[r].w);
    }
  }

  float* pp = P + ((size_t)blockIdx.z * B_ + b0 + rg * RPT) * N_T + 4 * cg;
#pragma unroll
  for (int r = 0; r < RPT; ++r) *(float4*)(pp + (size_t)r * N_T) = acc[r];
}

// ---------------- layer 5 (N=264, K=512, NSUM=16, SPLITK=4) ----------------
// grid = (1, 16, 4), block = 256
__global__ __launch_bounds__(256) void mlp_l5(
    const float* __restrict__ Pprev, const float* __restrict__ bias_in,
    const float* __restrict__ W5, float* __restrict__ P5) {
  __shared__ float sA[8][128];
  const int tid = threadIdx.x;
  const int b0 = blockIdx.y * 8;
  const int k0 = blockIdx.z * 128;
  {
    int g = tid >> 5, k4 = tid & 31;   // 8 rows x 32 float4 = 256 = THREADS
    float4 v = *(const float4*)(bias_in + k0 + 4 * k4);
    for (int s = 0; s < 16; ++s) {
      float4 p = *(const float4*)(Pprev + ((size_t)s * B_ + b0 + g) * 512 + k0 + 4 * k4);
      v.x += p.x; v.y += p.y; v.z += p.z; v.w += p.w;
    }
    v.x = fmaxf(v.x, 0.f); v.y = fmaxf(v.y, 0.f);
    v.z = fmaxf(v.z, 0.f); v.w = fmaxf(v.w, 0.f);
    *(float4*)&sA[g][4 * k4] = v;
  }
  __syncthreads();

  if (tid < 132) {
    float2 acc[8];
#pragma unroll
    for (int r = 0; r < 8; ++r) acc[r] = make_float2(0.f, 0.f);
    const float* wp = W5 + (size_t)k0 * 264 + 2 * tid;
#pragma unroll 4
    for (int k = 0; k < 128; ++k) {
      float2 w = *(const float2*)wp;
      wp += 264;
#pragma unroll
      for (int r = 0; r < 8; ++r) {
        float a = sA[r][k];
        acc[r].x = fmaf(a, w.x, acc[r].x);
        acc[r].y = fmaf(a, w.y, acc[r].y);
      }
    }
#pragma unroll
    for (int r = 0; r < 8; ++r)
      *(float2*)(P5 + ((size_t)blockIdx.z * B_ + b0 + r) * 264 + 2 * tid) = acc[r];
  }
}

// ---------------- ccc[b,c] = Re( conj(theta)^T T theta )  (raw) ----------------
__global__ __launch_bounds__(256) void ccc_kernel(
    const float* __restrict__ Tr, const float* __restrict__ Ti,
    const float* __restrict__ P5, const float* __restrict__ b5,
    float* __restrict__ ccc) {
  const int bc = blockIdx.x;
  const int b  = bc >> 6;
  const int tid = threadIdx.x;

  __shared__ __align__(16) float sx[104];
  __shared__ __align__(16) float sy[104];
  if (tid < 100) {
    float tr = b5[tid], ti = b5[100 + tid];
#pragma unroll
    for (int s = 0; s < 4; ++s) {
      tr += P5[(size_t)s * B_ * 264 + b * 264 + tid];
      ti += P5[(size_t)s * B_ * 264 + b * 264 + 100 + tid];
    }
    float inv = rsqrtf(fmaf(tr, tr, ti * ti));
    sx[tid] = tr * inv;
    sy[tid] = ti * inv;
  }
  __syncthreads();

  const float4* Tr4 = reinterpret_cast<const float4*>(Tr + (size_t)bc * 10000);
  const float4* Ti4 = reinterpret_cast<const float4*>(Ti + (size_t)bc * 10000);

  float acc = 0.f;
  for (int i = tid; i < 2500; i += 256) {
    float4 t = Tr4[i];
    float4 u = Ti4[i];
    int n  = i / 25;
    int m0 = (i - n * 25) * 4;
    float xn = sx[n], yn = sy[n];
    float4 xm = *reinterpret_cast<const float4*>(&sx[m0]);
    float4 ym = *reinterpret_cast<const float4*>(&sy[m0]);
    acc = fmaf(t.x, fmaf(xn, xm.x, yn * ym.x), acc);
    acc = fmaf(u.x, fmaf(yn, xm.x, -(xn * ym.x)), acc);
    acc = fmaf(t.y, fmaf(xn, xm.y, yn * ym.y), acc);
    acc = fmaf(u.y, fmaf(yn, xm.y, -(xn * ym.y)), acc);
    acc = fmaf(t.z, fmaf(xn, xm.z, yn * ym.z), acc);
    acc = fmaf(u.z, fmaf(yn, xm.z, -(xn * ym.z)), acc);
    acc = fmaf(t.w, fmaf(xn, xm.w, yn * ym.w), acc);
    acc = fmaf(u.w, fmaf(yn, xm.w, -(xn * ym.w)), acc);
  }

  for (int off = 32; off; off >>= 1) acc += __shfl_down(acc, off);
  __shared__ float sred[4];
  if ((tid & 63) == 0) sred[tid >> 6] = acc;
  __syncthreads();
  if (tid == 0) ccc[bc] = (sred[0] + sred[1]) + (sred[2] + sred[3]);
}

// ---------------- finalize ----------------
__global__ __launch_bounds__(256) void finalize_kernel(
    const float* __restrict__ P5, const float* __restrict__ b5,
    const float* __restrict__ ccc, float* __restrict__ out) {
  const int b = blockIdx.x;
  const int tid = threadIdx.x;
  __shared__ float s_t1[264];
  __shared__ float s_scale;

  for (int j = tid; j < 264; j += 256) {
    float v = b5[j];
#pragma unroll
    for (int s = 0; s < 4; ++s)
      v += P5[(size_t)s * B_ * 264 + b * 264 + j];
    s_t1[j] = v;
  }
  if (tid < 64) {
    float v = ccc[b * 64 + tid];
    for (int off = 32; off; off >>= 1) v = fmaxf(v, __shfl_down(v, off));
    if (tid == 0) s_scale = sqrtf(1e-15f / v);
  }
  __syncthreads();

  const float scale = s_scale;
  for (int j = tid; j < 264; j += 256) {
    float o;
    if (j < 200) {
      int n = (j < 100) ? j : (j - 100);
      float tr = s_t1[n];
      float ti = s_t1[100 + n];
      float inv = rsqrtf(fmaf(tr, tr, ti * ti));
      o = ((j < 100) ? tr : ti) * inv * scale;
    } else {
      o = s_t1[j];
    }
    out[b * 264 + j] = o;
  }
}

extern "C" void kernel_launch(void* const* d_in, const int* in_sizes, int n_in,
                              void* d_out, int out_size, void* d_ws, size_t ws_size,
                              hipStream_t stream) {
  const float* sample1 = (const float*)d_in[0];
  const float* Tr = (const float*)d_in[2];
  const float* Ti = (const float*)d_in[3];
  const float* W1 = (const float*)d_in[4];  const float* b1 = (const float*)d_in[5];
  const float* W2 = (const float*)d_in[6];  const float* b2 = (const float*)d_in[7];
  const float* W3 = (const float*)d_in[8];  const float* b3 = (const float*)d_in[9];
  const float* W4 = (const float*)d_in[10]; const float* b4 = (const float*)d_in[11];
  const float* W5 = (const float*)d_in[12]; const float* b5 = (const float*)d_in[13];

  float* ws = (float*)d_ws;
  float* Pa = ws;                        // max 16*128*1024 floats (8 MB)
  float* Pb = Pa + 16 * B_ * 1024;       // max 16*128*1024 floats (8 MB)
  float* P5 = Pb + 16 * B_ * 1024;       // 4*128*264
  float* cc = P5 + 4 * B_ * 264;         // 8192

  float* out = (float*)d_out;

  // L1: A[128,303] @ W1[303,1024], SPLITK=8 (KS=40) -> Pa[8][128][1024]
  mlp4<512, 8, 0, 1024, 40><<<dim3(1, 16, 8), 512, 0, stream>>>(sample1, nullptr, W1, Pa, 303);
  // L2: relu(Pa+b1) @ W2[1024,1024], SPLITK=16 -> Pb[16][128][1024]
  mlp4<512, 8, 8, 1024, 64><<<dim3(1, 16, 16), 512, 0, stream>>>(Pa, b1, W2, Pb, 1024);
  // L3: relu(Pb+b2) @ W3[1024,1024], SPLITK=16 -> Pa[16][128][1024]
  mlp4<512, 8, 16, 1024, 64><<<dim3(1, 16, 16), 512, 0, stream>>>(Pb, b2, W3, Pa, 1024);
  // L4: relu(Pa+b3) @ W4[1024,512], SPLITK=16 -> Pb[16][128][512]
  mlp4<512, 8, 16, 512, 64><<<dim3(1, 16, 16), 512, 0, stream>>>(Pa, b3, W4, Pb, 1024);
  // L5: relu(Pb+b4) @ W5[512,264], SPLITK=4 -> P5[4][128][264]
  mlp_l5<<<dim3(1, 16, 4), 256, 0, stream>>>(Pb, b4, W5, P5);

  ccc_kernel<<<dim3(B_ * 64), 256, 0, stream>>>(Tr, Ti, P5, b5, cc);
  finalize_kernel<<<dim3(B_), 256, 0, stream>>>(P5, b5, cc, out);
}

// Round 4
// 161.550 us; speedup vs baseline: 3.4057x; 1.1659x over previous
//
#include <hip/hip_runtime.h>

#define B_ 128   // batch

typedef __attribute__((ext_vector_type(4))) float f4;

// ---------------- split-K MLP layer, float4 cols, XCD-affinity swizzle ----------------
// P[z][b][j] = sum_{k in slice z} act[b,k] * W[k,j]
// act[b,k] = (NSUM==0) ? A[b,k] : relu(bias_in[k] + sum_s A[s][b][k])
// grid = (1, 16, SPLITK in {8,16}), block = THREADS
template<int THREADS, int BG, int NSUM, int N_T, int KS>
__global__ __launch_bounds__(THREADS) void mlp4(
    const float* __restrict__ A, const float* __restrict__ bias_in,
    const float* __restrict__ W, float* __restrict__ P, int K) {
  constexpr int G   = N_T / 4;        // col groups
  constexpr int NRG = THREADS / G;    // row groups
  constexpr int RPT = BG / NRG;       // rows per thread
  __shared__ float sA[BG][KS];

  // XCD-affinity: flat%8 == XCD; make z%8 == flat%8 so each W K-slice is
  // fetched by exactly one XCD (W HBM traffic 32MB -> 4MB per layer).
  const int flat = blockIdx.y + 16 * blockIdx.z;
  const int zz   = (flat & 7) + 8 * (flat >> 7);   // works for gridDim.z == 8 or 16
  const int yy   = (flat >> 3) & 15;

  const int tid = threadIdx.x;
  const int cg  = tid % G;
  const int rg  = tid / G;
  const int b0  = yy * BG;
  const int k0  = zz * KS;
  const int klen = (NSUM == 0) ? min(K - k0, KS) : KS;

  if (NSUM == 0) {
    for (int g = 0; g < BG; ++g)
      for (int k = tid; k < klen; k += THREADS)
        sA[g][k] = A[(size_t)(b0 + g) * K + k0 + k];
  } else {
    constexpr int K4 = KS / 4;
    for (int idx = tid; idx < BG * K4; idx += THREADS) {
      int g = idx / K4, k4 = idx % K4;
      float4 v = *(const float4*)(bias_in + k0 + 4 * k4);
      for (int s = 0; s < NSUM; ++s) {
        float4 p = *(const float4*)(A + ((size_t)s * B_ + b0 + g) * K + k0 + 4 * k4);
        v.x += p.x; v.y += p.y; v.z += p.z; v.w += p.w;
      }
      v.x = fmaxf(v.x, 0.f); v.y = fmaxf(v.y, 0.f);
      v.z = fmaxf(v.z, 0.f); v.w = fmaxf(v.w, 0.f);
      *(float4*)&sA[g][4 * k4] = v;
    }
  }
  __syncthreads();

  float4 acc[RPT];
#pragma unroll
  for (int r = 0; r < RPT; ++r) acc[r] = make_float4(0.f, 0.f, 0.f, 0.f);

  const float* wp = W + (size_t)k0 * N_T + 4 * cg;
#pragma unroll 4
  for (int k = 0; k < klen; ++k) {
    float4 w = *(const float4*)wp;
    wp += N_T;
#pragma unroll
    for (int r = 0; r < RPT; ++r) {
      float a = sA[rg * RPT + r][k];
      acc[r].x = fmaf(a, w.x, acc[r].x);
      acc[r].y = fmaf(a, w.y, acc[r].y);
      acc[r].z = fmaf(a, w.z, acc[r].z);
      acc[r].w = fmaf(a, w.w, acc[r].w);
    }
  }

  float* pp = P + ((size_t)zz * B_ + b0 + rg * RPT) * N_T + 4 * cg;
#pragma unroll
  for (int r = 0; r < RPT; ++r) *(float4*)(pp + (size_t)r * N_T) = acc[r];
}

// ---------------- layer 5 (N=264, K=512, NSUM=16, SPLITK=4) ----------------
// grid = (1, 16, 4), block = 256
__global__ __launch_bounds__(256) void mlp_l5(
    const float* __restrict__ Pprev, const float* __restrict__ bias_in,
    const float* __restrict__ W5, float* __restrict__ P5) {
  __shared__ float sA[8][128];
  const int tid = threadIdx.x;
  const int b0 = blockIdx.y * 8;
  const int k0 = blockIdx.z * 128;
  {
    int g = tid >> 5, k4 = tid & 31;
    float4 v = *(const float4*)(bias_in + k0 + 4 * k4);
    for (int s = 0; s < 16; ++s) {
      float4 p = *(const float4*)(Pprev + ((size_t)s * B_ + b0 + g) * 512 + k0 + 4 * k4);
      v.x += p.x; v.y += p.y; v.z += p.z; v.w += p.w;
    }
    v.x = fmaxf(v.x, 0.f); v.y = fmaxf(v.y, 0.f);
    v.z = fmaxf(v.z, 0.f); v.w = fmaxf(v.w, 0.f);
    *(float4*)&sA[g][4 * k4] = v;
  }
  __syncthreads();

  if (tid < 132) {
    float2 acc[8];
#pragma unroll
    for (int r = 0; r < 8; ++r) acc[r] = make_float2(0.f, 0.f);
    const float* wp = W5 + (size_t)k0 * 264 + 2 * tid;
#pragma unroll 4
    for (int k = 0; k < 128; ++k) {
      float2 w = *(const float2*)wp;
      wp += 264;
#pragma unroll
      for (int r = 0; r < 8; ++r) {
        float a = sA[r][k];
        acc[r].x = fmaf(a, w.x, acc[r].x);
        acc[r].y = fmaf(a, w.y, acc[r].y);
      }
    }
#pragma unroll
    for (int r = 0; r < 8; ++r)
      *(float2*)(P5 + ((size_t)blockIdx.z * B_ + b0 + r) * 264 + 2 * tid) = acc[r];
  }
}

// ---------------- ccc[b,c] = Re( conj(theta)^T T theta )  (raw) ----------------
// grid = B*C = 8192 blocks, block = 256. 4 independent accumulator chains.
__global__ __launch_bounds__(256) void ccc_kernel(
    const float* __restrict__ Tr, const float* __restrict__ Ti,
    const float* __restrict__ P5, const float* __restrict__ b5,
    float* __restrict__ ccc) {
  const int bc = blockIdx.x;
  const int b  = bc >> 6;
  const int tid = threadIdx.x;

  __shared__ __align__(16) float sx[104];
  __shared__ __align__(16) float sy[104];
  if (tid < 100) {
    float tr = b5[tid], ti = b5[100 + tid];
#pragma unroll
    for (int s = 0; s < 4; ++s) {
      tr += P5[(size_t)s * B_ * 264 + b * 264 + tid];
      ti += P5[(size_t)s * B_ * 264 + b * 264 + 100 + tid];
    }
    float inv = rsqrtf(fmaf(tr, tr, ti * ti));
    sx[tid] = tr * inv;
    sy[tid] = ti * inv;
  }
  __syncthreads();

  const f4* Tr4 = reinterpret_cast<const f4*>(Tr + (size_t)bc * 10000);
  const f4* Ti4 = reinterpret_cast<const f4*>(Ti + (size_t)bc * 10000);

  float a0 = 0.f, a1 = 0.f, a2 = 0.f, a3 = 0.f;
#pragma unroll 2
  for (int i = tid; i < 2500; i += 256) {
    f4 t = __builtin_nontemporal_load(Tr4 + i);
    f4 u = __builtin_nontemporal_load(Ti4 + i);
    int n  = i / 25;
    int m0 = (i - n * 25) * 4;
    float xn = sx[n], yn = sy[n];
    float4 xm = *reinterpret_cast<const float4*>(&sx[m0]);
    float4 ym = *reinterpret_cast<const float4*>(&sy[m0]);
    // Re = Tr*(xn*xm + yn*ym) + Ti*(yn*xm - xn*ym)
    a0 = fmaf(t.x, fmaf(xn, xm.x, yn * ym.x), a0);
    a1 = fmaf(u.x, fmaf(yn, xm.x, -(xn * ym.x)), a1);
    a2 = fmaf(t.y, fmaf(xn, xm.y, yn * ym.y), a2);
    a3 = fmaf(u.y, fmaf(yn, xm.y, -(xn * ym.y)), a3);
    a0 = fmaf(t.z, fmaf(xn, xm.z, yn * ym.z), a0);
    a1 = fmaf(u.z, fmaf(yn, xm.z, -(xn * ym.z)), a1);
    a2 = fmaf(t.w, fmaf(xn, xm.w, yn * ym.w), a2);
    a3 = fmaf(u.w, fmaf(yn, xm.w, -(xn * ym.w)), a3);
  }
  float acc = (a0 + a1) + (a2 + a3);

  for (int off = 32; off; off >>= 1) acc += __shfl_down(acc, off);
  __shared__ float sred[4];
  if ((tid & 63) == 0) sred[tid >> 6] = acc;
  __syncthreads();
  if (tid == 0) ccc[bc] = (sred[0] + sred[1]) + (sred[2] + sred[3]);
}

// ---------------- finalize ----------------
__global__ __launch_bounds__(256) void finalize_kernel(
    const float* __restrict__ P5, const float* __restrict__ b5,
    const float* __restrict__ ccc, float* __restrict__ out) {
  const int b = blockIdx.x;
  const int tid = threadIdx.x;
  __shared__ float s_t1[264];
  __shared__ float s_scale;

  for (int j = tid; j < 264; j += 256) {
    float v = b5[j];
#pragma unroll
    for (int s = 0; s < 4; ++s)
      v += P5[(size_t)s * B_ * 264 + b * 264 + j];
    s_t1[j] = v;
  }
  if (tid < 64) {
    float v = ccc[b * 64 + tid];
    for (int off = 32; off; off >>= 1) v = fmaxf(v, __shfl_down(v, off));
    if (tid == 0) s_scale = sqrtf(1e-15f / v);
  }
  __syncthreads();

  const float scale = s_scale;
  for (int j = tid; j < 264; j += 256) {
    float o;
    if (j < 200) {
      int n = (j < 100) ? j : (j - 100);
      float tr = s_t1[n];
      float ti = s_t1[100 + n];
      float inv = rsqrtf(fmaf(tr, tr, ti * ti));
      o = ((j < 100) ? tr : ti) * inv * scale;
    } else {
      o = s_t1[j];
    }
    out[b * 264 + j] = o;
  }
}

extern "C" void kernel_launch(void* const* d_in, const int* in_sizes, int n_in,
                              void* d_out, int out_size, void* d_ws, size_t ws_size,
                              hipStream_t stream) {
  const float* sample1 = (const float*)d_in[0];
  const float* Tr = (const float*)d_in[2];
  const float* Ti = (const float*)d_in[3];
  const float* W1 = (const float*)d_in[4];  const float* b1 = (const float*)d_in[5];
  const float* W2 = (const float*)d_in[6];  const float* b2 = (const float*)d_in[7];
  const float* W3 = (const float*)d_in[8];  const float* b3 = (const float*)d_in[9];
  const float* W4 = (const float*)d_in[10]; const float* b4 = (const float*)d_in[11];
  const float* W5 = (const float*)d_in[12]; const float* b5 = (const float*)d_in[13];

  float* ws = (float*)d_ws;
  float* Pa = ws;                        // max 16*128*1024 floats (8 MB)
  float* Pb = Pa + 16 * B_ * 1024;       // max 16*128*1024 floats (8 MB)
  float* P5 = Pb + 16 * B_ * 1024;       // 4*128*264
  float* cc = P5 + 4 * B_ * 264;         // 8192

  float* out = (float*)d_out;

  // L1: A[128,303] @ W1[303,1024], SPLITK=8 (KS=40) -> Pa[8][128][1024]
  mlp4<512, 8, 0, 1024, 40><<<dim3(1, 16, 8), 512, 0, stream>>>(sample1, nullptr, W1, Pa, 303);
  // L2: relu(Pa+b1) @ W2[1024,1024], SPLITK=16 -> Pb[16][128][1024]
  mlp4<512, 8, 8, 1024, 64><<<dim3(1, 16, 16), 512, 0, stream>>>(Pa, b1, W2, Pb, 1024);
  // L3: relu(Pb+b2) @ W3[1024,1024], SPLITK=16 -> Pa[16][128][1024]
  mlp4<512, 8, 16, 1024, 64><<<dim3(1, 16, 16), 512, 0, stream>>>(Pb, b2, W3, Pa, 1024);
  // L4: relu(Pa+b3) @ W4[1024,512], SPLITK=16 -> Pb[16][128][512]
  mlp4<512, 8, 16, 512, 64><<<dim3(1, 16, 16), 512, 0, stream>>>(Pa, b3, W4, Pb, 1024);
  // L5: relu(Pb+b4) @ W5[512,264], SPLITK=4 -> P5[4][128][264]
  mlp_l5<<<dim3(1, 16, 4), 256, 0, stream>>>(Pb, b4, W5, P5);

  ccc_kernel<<<dim3(B_ * 64), 256, 0, stream>>>(Tr, Ti, P5, b5, cc);
  finalize_kernel<<<dim3(B_), 256, 0, stream>>>(P5, b5, cc, out);
}

// Round 5
// 158.089 us; speedup vs baseline: 3.4803x; 1.0219x over previous
//
#include <hip/hip_runtime.h>

#define B_ 128   // batch

typedef __attribute__((ext_vector_type(4))) float f4;
typedef __attribute__((ext_vector_type(2))) float f2;

// ---------------- split-K MLP layer, k-major LDS + packed-FMA ----------------
// P[z][b][j] = sum_{k in slice z} act[b,k] * W[k,j]
// act[b,k] = (NSUM==0) ? A[b,k] : relu(bias_in[k] + sum_s A[s][b][k])
// grid = (1, 16, SPLITK in {8,16}), block = THREADS
template<int THREADS, int BG, int NSUM, int N_T, int KS>
__global__ __launch_bounds__(THREADS) void mlp4(
    const float* __restrict__ A, const float* __restrict__ bias_in,
    const float* __restrict__ W, float* __restrict__ P, int K) {
  constexpr int G   = N_T / 4;        // col groups (threads per row-group)
  constexpr int NRG = THREADS / G;    // row groups
  constexpr int RPT = BG / NRG;       // rows per thread (4 or 2)
  __shared__ float sA[KS][BG];        // k-major: sA[k][row]

  // XCD-affinity: flat%8 == XCD; z%8 == flat%8 so each W K-slice stays on one XCD.
  const int flat = blockIdx.y + 16 * blockIdx.z;
  const int zz   = (flat & 7) + 8 * (flat >> 7);   // valid for gridDim.z == 8 or 16
  const int yy   = (flat >> 3) & 15;

  const int tid = threadIdx.x;
  const int cg  = tid % G;
  const int rg  = tid / G;
  const int b0  = yy * BG;
  const int k0  = zz * KS;
  const int klen = (NSUM == 0) ? min(K - k0, KS) : KS;

  if (NSUM == 0) {
    for (int g = 0; g < BG; ++g)
      for (int k = tid; k < klen; k += THREADS)
        sA[k][g] = A[(size_t)(b0 + g) * K + k0 + k];   // coalesced global read
  } else {
    constexpr int K4 = KS / 4;
    for (int idx = tid; idx < BG * K4; idx += THREADS) {
      int g = idx / K4, k4 = idx % K4;
      f4 v = *(const f4*)(bias_in + k0 + 4 * k4);
      for (int s = 0; s < NSUM; ++s)
        v += *(const f4*)(A + ((size_t)s * B_ + b0 + g) * K + k0 + 4 * k4);
      v.x = fmaxf(v.x, 0.f); v.y = fmaxf(v.y, 0.f);
      v.z = fmaxf(v.z, 0.f); v.w = fmaxf(v.w, 0.f);
      sA[4 * k4 + 0][g] = v.x;
      sA[4 * k4 + 1][g] = v.y;
      sA[4 * k4 + 2][g] = v.z;
      sA[4 * k4 + 3][g] = v.w;
    }
  }
  __syncthreads();

  f4 acc[RPT];
#pragma unroll
  for (int r = 0; r < RPT; ++r) acc[r] = (f4)0.f;

  const float* wp = W + (size_t)k0 * N_T + 4 * cg;
#pragma unroll 8
  for (int k = 0; k < klen; ++k) {
    f4 w = *(const f4*)wp;           // global float4 (L2-resident after swizzle)
    wp += N_T;
    if constexpr (RPT == 4) {
      f4 a = *(const f4*)&sA[k][rg * 4];   // one ds_read_b128, broadcast
#pragma unroll
      for (int r = 0; r < 4; ++r) acc[r] += a[r] * w;   // v_pk_fma_f32 pairs
    } else {
      f2 a = *(const f2*)&sA[k][rg * 2];   // one ds_read_b64, broadcast
#pragma unroll
      for (int r = 0; r < 2; ++r) acc[r] += a[r] * w;
    }
  }

  float* pp = P + ((size_t)zz * B_ + b0 + rg * RPT) * N_T + 4 * cg;
#pragma unroll
  for (int r = 0; r < RPT; ++r) *(f4*)(pp + (size_t)r * N_T) = acc[r];
}

// ---------------- layer 5 (N=264, K=512, NSUM=16, SPLITK=4) ----------------
// grid = (1, 16, 4), block = 256
__global__ __launch_bounds__(256) void mlp_l5(
    const float* __restrict__ Pprev, const float* __restrict__ bias_in,
    const float* __restrict__ W5, float* __restrict__ P5) {
  __shared__ float sA[8][128];
  const int tid = threadIdx.x;
  const int b0 = blockIdx.y * 8;
  const int k0 = blockIdx.z * 128;
  {
    int g = tid >> 5, k4 = tid & 31;
    f4 v = *(const f4*)(bias_in + k0 + 4 * k4);
    for (int s = 0; s < 16; ++s)
      v += *(const f4*)(Pprev + ((size_t)s * B_ + b0 + g) * 512 + k0 + 4 * k4);
    v.x = fmaxf(v.x, 0.f); v.y = fmaxf(v.y, 0.f);
    v.z = fmaxf(v.z, 0.f); v.w = fmaxf(v.w, 0.f);
    *(f4*)&sA[g][4 * k4] = v;
  }
  __syncthreads();

  if (tid < 132) {
    f2 acc[8];
#pragma unroll
    for (int r = 0; r < 8; ++r) acc[r] = (f2)0.f;
    const float* wp = W5 + (size_t)k0 * 264 + 2 * tid;
#pragma unroll 4
    for (int k = 0; k < 128; ++k) {
      f2 w = *(const f2*)wp;
      wp += 264;
#pragma unroll
      for (int r = 0; r < 8; ++r) acc[r] += sA[r][k] * w;
    }
#pragma unroll
    for (int r = 0; r < 8; ++r)
      *(f2*)(P5 + ((size_t)blockIdx.z * B_ + b0 + r) * 264 + 2 * tid) = acc[r];
  }
}

// ---------------- ccc[b,c] = Re( conj(theta)^T T theta )  (raw) ----------------
__global__ __launch_bounds__(256) void ccc_kernel(
    const float* __restrict__ Tr, const float* __restrict__ Ti,
    const float* __restrict__ P5, const float* __restrict__ b5,
    float* __restrict__ ccc) {
  const int bc = blockIdx.x;
  const int b  = bc >> 6;
  const int tid = threadIdx.x;

  __shared__ __align__(16) float sx[104];
  __shared__ __align__(16) float sy[104];
  if (tid < 100) {
    float tr = b5[tid], ti = b5[100 + tid];
#pragma unroll
    for (int s = 0; s < 4; ++s) {
      tr += P5[(size_t)s * B_ * 264 + b * 264 + tid];
      ti += P5[(size_t)s * B_ * 264 + b * 264 + 100 + tid];
    }
    float inv = rsqrtf(fmaf(tr, tr, ti * ti));
    sx[tid] = tr * inv;
    sy[tid] = ti * inv;
  }
  __syncthreads();

  const f4* Tr4 = reinterpret_cast<const f4*>(Tr + (size_t)bc * 10000);
  const f4* Ti4 = reinterpret_cast<const f4*>(Ti + (size_t)bc * 10000);

  float a0 = 0.f, a1 = 0.f, a2 = 0.f, a3 = 0.f;
#pragma unroll 2
  for (int i = tid; i < 2500; i += 256) {
    f4 t = __builtin_nontemporal_load(Tr4 + i);
    f4 u = __builtin_nontemporal_load(Ti4 + i);
    int n  = i / 25;
    int m0 = (i - n * 25) * 4;
    float xn = sx[n], yn = sy[n];
    float4 xm = *reinterpret_cast<const float4*>(&sx[m0]);
    float4 ym = *reinterpret_cast<const float4*>(&sy[m0]);
    a0 = fmaf(t.x, fmaf(xn, xm.x, yn * ym.x), a0);
    a1 = fmaf(u.x, fmaf(yn, xm.x, -(xn * ym.x)), a1);
    a2 = fmaf(t.y, fmaf(xn, xm.y, yn * ym.y), a2);
    a3 = fmaf(u.y, fmaf(yn, xm.y, -(xn * ym.y)), a3);
    a0 = fmaf(t.z, fmaf(xn, xm.z, yn * ym.z), a0);
    a1 = fmaf(u.z, fmaf(yn, xm.z, -(xn * ym.z)), a1);
    a2 = fmaf(t.w, fmaf(xn, xm.w, yn * ym.w), a2);
    a3 = fmaf(u.w, fmaf(yn, xm.w, -(xn * ym.w)), a3);
  }
  float acc = (a0 + a1) + (a2 + a3);

  for (int off = 32; off; off >>= 1) acc += __shfl_down(acc, off);
  __shared__ float sred[4];
  if ((tid & 63) == 0) sred[tid >> 6] = acc;
  __syncthreads();
  if (tid == 0) ccc[bc] = (sred[0] + sred[1]) + (sred[2] + sred[3]);
}

// ---------------- finalize ----------------
__global__ __launch_bounds__(256) void finalize_kernel(
    const float* __restrict__ P5, const float* __restrict__ b5,
    const float* __restrict__ ccc, float* __restrict__ out) {
  const int b = blockIdx.x;
  const int tid = threadIdx.x;
  __shared__ float s_t1[264];
  __shared__ float s_scale;

  for (int j = tid; j < 264; j += 256) {
    float v = b5[j];
#pragma unroll
    for (int s = 0; s < 4; ++s)
      v += P5[(size_t)s * B_ * 264 + b * 264 + j];
    s_t1[j] = v;
  }
  if (tid < 64) {
    float v = ccc[b * 64 + tid];
    for (int off = 32; off; off >>= 1) v = fmaxf(v, __shfl_down(v, off));
    if (tid == 0) s_scale = sqrtf(1e-15f / v);
  }
  __syncthreads();

  const float scale = s_scale;
  for (int j = tid; j < 264; j += 256) {
    float o;
    if (j < 200) {
      int n = (j < 100) ? j : (j - 100);
      float tr = s_t1[n];
      float ti = s_t1[100 + n];
      float inv = rsqrtf(fmaf(tr, tr, ti * ti));
      o = ((j < 100) ? tr : ti) * inv * scale;
    } else {
      o = s_t1[j];
    }
    out[b * 264 + j] = o;
  }
}

extern "C" void kernel_launch(void* const* d_in, const int* in_sizes, int n_in,
                              void* d_out, int out_size, void* d_ws, size_t ws_size,
                              hipStream_t stream) {
  const float* sample1 = (const float*)d_in[0];
  const float* Tr = (const float*)d_in[2];
  const float* Ti = (const float*)d_in[3];
  const float* W1 = (const float*)d_in[4];  const float* b1 = (const float*)d_in[5];
  const float* W2 = (const float*)d_in[6];  const float* b2 = (const float*)d_in[7];
  const float* W3 = (const float*)d_in[8];  const float* b3 = (const float*)d_in[9];
  const float* W4 = (const float*)d_in[10]; const float* b4 = (const float*)d_in[11];
  const float* W5 = (const float*)d_in[12]; const float* b5 = (const float*)d_in[13];

  float* ws = (float*)d_ws;
  float* Pa = ws;                        // 16*128*1024 floats (8 MB)
  float* Pb = Pa + 16 * B_ * 1024;       // 16*128*1024 floats (8 MB)
  float* P5 = Pb + 16 * B_ * 1024;       // 4*128*264
  float* cc = P5 + 4 * B_ * 264;         // 8192

  float* out = (float*)d_out;

  // L1: A[128,303] @ W1[303,1024], SPLITK=8 (KS=40) -> Pa[8][128][1024]
  mlp4<512, 8, 0, 1024, 40><<<dim3(1, 16, 8), 512, 0, stream>>>(sample1, nullptr, W1, Pa, 303);
  // L2: relu(Pa+b1) @ W2[1024,1024], SPLITK=16 -> Pb[16][128][1024]
  mlp4<512, 8, 8, 1024, 64><<<dim3(1, 16, 16), 512, 0, stream>>>(Pa, b1, W2, Pb, 1024);
  // L3: relu(Pb+b2) @ W3[1024,1024], SPLITK=16 -> Pa[16][128][1024]
  mlp4<512, 8, 16, 1024, 64><<<dim3(1, 16, 16), 512, 0, stream>>>(Pb, b2, W3, Pa, 1024);
  // L4: relu(Pa+b3) @ W4[1024,512], SPLITK=16 -> Pb[16][128][512]
  mlp4<512, 8, 16, 512, 64><<<dim3(1, 16, 16), 512, 0, stream>>>(Pa, b3, W4, Pb, 1024);
  // L5: relu(Pb+b4) @ W5[512,264], SPLITK=4 -> P5[4][128][264]
  mlp_l5<<<dim3(1, 16, 4), 256, 0, stream>>>(Pb, b4, W5, P5);

  ccc_kernel<<<dim3(B_ * 64), 256, 0, stream>>>(Tr, Ti, P5, b5, cc);
  finalize_kernel<<<dim3(B_), 256, 0, stream>>>(P5, b5, cc, out);
}